// Round 4
// baseline (26918.710 us; speedup 1.0000x reference)
//
#include <hip/hip_runtime.h>
#include <math.h>

#define HID   256
#define TLEN  512
#define BB    32            // batch per block
#define NTHR  1024          // 16 waves, 1 block/CU, 4 waves/SIMD

typedef __attribute__((ext_vector_type(8))) short short8;
typedef __attribute__((ext_vector_type(4))) float f32x4;

static __device__ __forceinline__ unsigned short f2bf_rne(float x) {
    unsigned int u = __float_as_uint(x);
    unsigned int r = (u + 0x7FFFu + ((u >> 16) & 1u)) >> 16;
    return (unsigned short)r;
}
static __device__ __forceinline__ float bf2f(unsigned short h) {
    return __uint_as_float(((unsigned int)h) << 16);
}
static __device__ __forceinline__ float sigf(float x) {
    return 1.0f / (1.0f + __expf(-x));
}
static __device__ __forceinline__ float tanhf_fast(float x) {
    return 1.0f - 2.0f / (1.0f + __expf(2.0f * x));
}

// ---- pack W_hh (f32 row-major [1024][256]) into MFMA B-fragment order ----
// tile t_idx = gt*8 + kc  (gt: 16-row gate tile, kc: 32-wide k chunk)
// wp[t_idx*128 + sel*64 + lane] = short8 of W[16gt+(l&15)][32kc+8(l>>4) .. +7]
// sel 0 = hi bf16, sel 1 = lo bf16 (residual)
__global__ void pack_whh(const float* __restrict__ W, unsigned short* __restrict__ wp) {
    int idx  = blockIdx.x * 256 + threadIdx.x;   // 32768 total
    int lane = idx & 63;
    int t_idx = idx >> 6;                        // 0..511
    int gt = t_idx >> 3, kc = t_idx & 7;
    int g  = gt * 16 + (lane & 15);
    int k0 = kc * 32 + (lane >> 4) * 8;
    const float* src = W + (size_t)g * HID + k0;
    unsigned short* dhi = wp + ((size_t)t_idx * 128 + lane) * 8;
    unsigned short* dlo = wp + ((size_t)t_idx * 128 + 64 + lane) * 8;
    #pragma unroll
    for (int e = 0; e < 8; ++e) {
        float x = src[e];
        unsigned short hi = f2bf_rne(x);
        float res = x - bf2f(hi);
        dhi[e] = hi;
        dlo[e] = f2bf_rne(res);
    }
}

__global__ __launch_bounds__(NTHR, 4) void lstm_mfma3(
    const float* __restrict__ x,      // (B,1,1)
    const float* __restrict__ W_ih,   // (1024,)
    const float* __restrict__ b_ih,   // (1024,)
    const float* __restrict__ b_hh,   // (1024,)
    const float* __restrict__ W_fc,   // (256,)
    const float* __restrict__ b_fc,   // (1,)
    const short8* __restrict__ wp,    // packed split-bf16 W_hh
    float* __restrict__ out)          // (B, 512)
{
    const int tid  = threadIdx.x;
    const int wave = tid >> 6;        // 0..15 : owns j-slice [wave*16, wave*16+16)
    const int lane = tid & 63;
    const int l15  = lane & 15;
    const int l4   = lane >> 4;
    const int bbase = blockIdx.x * BB;

    // h planes in MFMA A-fragment order, double-buffered:
    // tile (m,kc) at [(m*8+kc)*512 ..]; element (row,kw) at lane'=row+16*(kw>>3), elem=kw&7
    __shared__ unsigned short hhi[2][16 * 512];   // 2 x 16 KiB
    __shared__ unsigned short hlo[2][16 * 512];   // 2 x 16 KiB
    __shared__ float dpart[16][32];
    __shared__ float inp_s[BB];

    for (int i = tid; i < 16 * 512; i += NTHR) { hhi[0][i] = 0; hlo[0][i] = 0; }
    if (tid < BB) inp_s[tid] = x[bbase + tid];

    // per-lane constants: gate row g = q*256 + wave*16 + l15
    float biasv[4], wihv[4];
    #pragma unroll
    for (int q = 0; q < 4; ++q) {
        int g = 256 * q + 16 * wave + l15;
        biasv[q] = b_ih[g] + b_hh[g];
        wihv[q]  = W_ih[g];
    }
    const float wfc = W_fc[16 * wave + l15];
    const float bfc = b_fc[0];

    // h-write address (step-invariant parts): j = wave*16+l15
    const int kc_w  = wave >> 1;                       // j>>5
    const int kwhi  = (wave & 1) * 2 + (l15 >> 3);     // (j&31)>>3
    const int elemw = l15 & 7;

    float c_r[2][4];
    #pragma unroll
    for (int m = 0; m < 2; ++m)
        #pragma unroll
        for (int r = 0; r < 4; ++r) c_r[m][r] = 0.0f;

    __syncthreads();

    #pragma unroll 1
    for (int t = 0; t < TLEN; ++t) {
        const int p = t & 1;

        // ---- acc init: bias + d*W_ih ----
        f32x4 acc[2][4];
        {
            float dv[2][4];
            #pragma unroll
            for (int m = 0; m < 2; ++m)
                #pragma unroll
                for (int r = 0; r < 4; ++r)
                    dv[m][r] = inp_s[16 * m + 4 * l4 + r];
            #pragma unroll
            for (int m = 0; m < 2; ++m)
                #pragma unroll
                for (int q = 0; q < 4; ++q)
                    #pragma unroll
                    for (int r = 0; r < 4; ++r)
                        acc[m][q][r] = fmaf(dv[m][r], wihv[q], biasv[q]);
        }

        // ---- MFMA: gates += h @ W_hh^T (3-term split bf16) ----
        #pragma unroll
        for (int kc = 0; kc < 8; ++kc) {
            short8 ahi[2], alo[2];
            #pragma unroll
            for (int m = 0; m < 2; ++m) {
                int aoff = (m * 8 + kc) * 512 + lane * 8;
                ahi[m] = *(const short8*)&hhi[p][aoff];
                alo[m] = *(const short8*)&hlo[p][aoff];
            }
            #pragma unroll
            for (int q = 0; q < 4; ++q) {
                int gt = q * 16 + wave;
                size_t idx = (size_t)(gt * 8 + kc) * 128 + lane;
                short8 bhi = wp[idx];
                short8 blo = wp[idx + 64];
                #pragma unroll
                for (int m = 0; m < 2; ++m) {
                    acc[m][q] = __builtin_amdgcn_mfma_f32_16x16x32_bf16(ahi[m], bhi, acc[m][q], 0, 0, 0);
                    acc[m][q] = __builtin_amdgcn_mfma_f32_16x16x32_bf16(alo[m], bhi, acc[m][q], 0, 0, 0);
                    acc[m][q] = __builtin_amdgcn_mfma_f32_16x16x32_bf16(ahi[m], blo, acc[m][q], 0, 0, 0);
                }
            }
        }

        // ---- cell update (i,f,g,o same lane) + h write (other buffer) + d partials ----
        float ps[2][4];
        #pragma unroll
        for (int m = 0; m < 2; ++m) {
            #pragma unroll
            for (int r = 0; r < 4; ++r) {
                float gi = acc[m][0][r];
                float gf = acc[m][1][r];
                float gg = acc[m][2][r];
                float go = acc[m][3][r];
                float c  = c_r[m][r];
                c = fmaf(sigf(gf), c, sigf(gi) * tanhf_fast(gg));
                c_r[m][r] = c;
                float h = sigf(go) * tanhf_fast(c);
                unsigned short hh = f2bf_rne(h);
                float hres = h - bf2f(hh);
                int haddr = (m * 8 + kc_w) * 512
                          + ((4 * l4 + r) + 16 * kwhi) * 8 + elemw;
                hhi[p ^ 1][haddr] = hh;
                hlo[p ^ 1][haddr] = f2bf_rne(hres);
                ps[m][r] = h * wfc;
            }
        }

        // reduce d partials over the 16-lane j-group
        #pragma unroll
        for (int m = 0; m < 2; ++m)
            #pragma unroll
            for (int r = 0; r < 4; ++r) {
                float s = ps[m][r];
                s += __shfl_xor(s, 1);
                s += __shfl_xor(s, 2);
                s += __shfl_xor(s, 4);
                s += __shfl_xor(s, 8);
                if (l15 == 0) dpart[wave][16 * m + 4 * l4 + r] = s;
            }
        __syncthreads();   // B_A: h(alt buf) + dpart visible

        // ---- final d = sum over 16 waves + b_fc ; feedback ----
        if (tid < BB) {
            float s = bfc;
            #pragma unroll
            for (int w = 0; w < 16; ++w) s += dpart[w][tid];
            inp_s[tid] = s;
            out[(size_t)(bbase + tid) * TLEN + t] = s;
        }
        __syncthreads();   // B_B: inp_s ready; weight/h reads of next step may begin
    }
}

extern "C" void kernel_launch(void* const* d_in, const int* in_sizes, int n_in,
                              void* d_out, int out_size, void* d_ws, size_t ws_size,
                              hipStream_t stream) {
    const float* x    = (const float*)d_in[0];
    const float* W_ih = (const float*)d_in[1];
    const float* W_hh = (const float*)d_in[2];
    const float* b_ih = (const float*)d_in[3];
    const float* b_hh = (const float*)d_in[4];
    const float* W_fc = (const float*)d_in[5];
    const float* b_fc = (const float*)d_in[6];
    float* out = (float*)d_out;

    const int BATCH   = in_sizes[0];        // 8192
    const int nblocks = BATCH / BB;         // 256 -> 1 block/CU

    pack_whh<<<128, 256, 0, stream>>>(W_hh, (unsigned short*)d_ws);
    lstm_mfma3<<<nblocks, NTHR, 0, stream>>>(
        x, W_ih, b_ih, b_hh, W_fc, b_fc, (const short8*)d_ws, out);
}

// Round 5
// 26473.355 us; speedup vs baseline: 1.0168x; 1.0168x over previous
//
#include <hip/hip_runtime.h>
#include <math.h>

#define HID   256
#define TLEN  512
#define BB    32            // batch per block
#define NTHR  1024          // 16 waves, 1 block/CU, 4 waves/SIMD

#define WP_SHORT8 (512 * 128)        // packed weight image size in short8 units
#define WP_BYTES  (WP_SHORT8 * 16)   // 1 MiB

typedef __attribute__((ext_vector_type(8))) short short8;
typedef __attribute__((ext_vector_type(4))) float f32x4;

static __device__ __forceinline__ unsigned short f2bf_rne(float x) {
    unsigned int u = __float_as_uint(x);
    unsigned int r = (u + 0x7FFFu + ((u >> 16) & 1u)) >> 16;
    return (unsigned short)r;
}
static __device__ __forceinline__ float bf2f(unsigned short h) {
    return __uint_as_float(((unsigned int)h) << 16);
}
static __device__ __forceinline__ float sigf(float x) {
    return 1.0f / (1.0f + __expf(-x));
}
static __device__ __forceinline__ float tanhf_fast(float x) {
    return 1.0f - 2.0f / (1.0f + __expf(2.0f * x));
}

// ---- pack W_hh (f32 row-major [1024][256]) into MFMA B-fragment order ----
// One copy per blockIdx.y (weight image replicated to decorrelate XCD traffic).
// tile t_idx = gt*8 + kc  (gt: 16-row gate tile, kc: 32-wide k chunk)
// wp[t_idx*128 + sel*64 + lane] = short8 of W[16gt+(l&15)][32kc+8(l>>4) .. +7]
// sel 0 = hi bf16, sel 1 = lo bf16 (residual)
__global__ void pack_whh(const float* __restrict__ W, unsigned short* __restrict__ wp_base) {
    unsigned short* wp = wp_base + (size_t)blockIdx.y * (WP_SHORT8 * 8);
    int idx  = blockIdx.x * 256 + threadIdx.x;   // 32768 total per copy
    int lane = idx & 63;
    int t_idx = idx >> 6;                        // 0..511
    int gt = t_idx >> 3, kc = t_idx & 7;
    int g  = gt * 16 + (lane & 15);
    int k0 = kc * 32 + (lane >> 4) * 8;
    const float* src = W + (size_t)g * HID + k0;
    unsigned short* dhi = wp + ((size_t)t_idx * 128 + lane) * 8;
    unsigned short* dlo = wp + ((size_t)t_idx * 128 + 64 + lane) * 8;
    #pragma unroll
    for (int e = 0; e < 8; ++e) {
        float x = src[e];
        unsigned short hi = f2bf_rne(x);
        float res = x - bf2f(hi);
        dhi[e] = hi;
        dlo[e] = f2bf_rne(res);
    }
}

__global__ __launch_bounds__(NTHR, 4) void lstm_mfma4(
    const float* __restrict__ x,      // (B,1,1)
    const float* __restrict__ W_ih,   // (1024,)
    const float* __restrict__ b_ih,   // (1024,)
    const float* __restrict__ b_hh,   // (1024,)
    const float* __restrict__ W_fc,   // (256,)
    const float* __restrict__ b_fc,   // (1,)
    const short8* __restrict__ wp_base, // packed split-bf16 W_hh (replicated)
    int copy_mask,                    // ncopies-1 (pow2-1)
    float* __restrict__ out)          // (B, 512)
{
    const int tid  = threadIdx.x;
    const int wave = tid >> 6;        // 0..15 : owns j-slice [wave*16, wave*16+16)
    const int lane = tid & 63;
    const int l15  = lane & 15;
    const int l4   = lane >> 4;
    const int bbase = blockIdx.x * BB;

    // per-XCD weight copy: blockIdx round-robins XCDs, so &7 ~ XCD id
    const short8* __restrict__ wp = wp_base
        + (size_t)(blockIdx.x & copy_mask) * WP_SHORT8;

    // h planes in MFMA A-fragment order, double-buffered:
    // tile (m,kc) at [(m*8+kc)*512 ..]; element (row,kw) at lane'=row+16*(kw>>3), elem=kw&7
    __shared__ unsigned short hhi[2][16 * 512];   // 2 x 16 KiB
    __shared__ unsigned short hlo[2][16 * 512];   // 2 x 16 KiB
    __shared__ float dpart[16][32];
    __shared__ float inp_s[BB];

    for (int i = tid; i < 16 * 512; i += NTHR) { hhi[0][i] = 0; hlo[0][i] = 0; }
    if (tid < BB) inp_s[tid] = x[bbase + tid];

    // per-lane constants: gate row g = q*256 + wave*16 + l15
    float biasv[4], wihv[4];
    #pragma unroll
    for (int q = 0; q < 4; ++q) {
        int g = 256 * q + 16 * wave + l15;
        biasv[q] = b_ih[g] + b_hh[g];
        wihv[q]  = W_ih[g];
    }
    const float wfc = W_fc[16 * wave + l15];
    const float bfc = b_fc[0];

    // h-write address (step-invariant parts): j = wave*16+l15
    const int kc_w  = wave >> 1;                       // j>>5
    const int kwhi  = (wave & 1) * 2 + (l15 >> 3);     // (j&31)>>3
    const int elemw = l15 & 7;

    float c_r[2][4];
    #pragma unroll
    for (int m = 0; m < 2; ++m)
        #pragma unroll
        for (int r = 0; r < 4; ++r) c_r[m][r] = 0.0f;

    __syncthreads();

    #pragma unroll 1
    for (int t = 0; t < TLEN; ++t) {
        const int p = t & 1;

        // ---- acc init: bias + d*W_ih ----
        f32x4 acc[2][4];
        {
            float dv[2][4];
            #pragma unroll
            for (int m = 0; m < 2; ++m)
                #pragma unroll
                for (int r = 0; r < 4; ++r)
                    dv[m][r] = inp_s[16 * m + 4 * l4 + r];
            #pragma unroll
            for (int m = 0; m < 2; ++m)
                #pragma unroll
                for (int q = 0; q < 4; ++q)
                    #pragma unroll
                    for (int r = 0; r < 4; ++r)
                        acc[m][q][r] = fmaf(dv[m][r], wihv[q], biasv[q]);
        }

        // ---- MFMA: gates += h @ W_hh^T (3-term split bf16) ----
        #pragma unroll
        for (int kc = 0; kc < 8; ++kc) {
            short8 ahi[2], alo[2];
            #pragma unroll
            for (int m = 0; m < 2; ++m) {
                int aoff = (m * 8 + kc) * 512 + lane * 8;
                ahi[m] = *(const short8*)&hhi[p][aoff];
                alo[m] = *(const short8*)&hlo[p][aoff];
            }
            #pragma unroll
            for (int q = 0; q < 4; ++q) {
                int gt = q * 16 + wave;
                size_t idx = (size_t)(gt * 8 + kc) * 128 + lane;
                short8 bhi = wp[idx];
                short8 blo = wp[idx + 64];
                #pragma unroll
                for (int m = 0; m < 2; ++m) {
                    acc[m][q] = __builtin_amdgcn_mfma_f32_16x16x32_bf16(ahi[m], bhi, acc[m][q], 0, 0, 0);
                    acc[m][q] = __builtin_amdgcn_mfma_f32_16x16x32_bf16(alo[m], bhi, acc[m][q], 0, 0, 0);
                    acc[m][q] = __builtin_amdgcn_mfma_f32_16x16x32_bf16(ahi[m], blo, acc[m][q], 0, 0, 0);
                }
            }
        }

        // ---- cell update (i,f,g,o same lane) + h write (other buffer) + d partials ----
        float ps[2][4];
        #pragma unroll
        for (int m = 0; m < 2; ++m) {
            #pragma unroll
            for (int r = 0; r < 4; ++r) {
                float gi = acc[m][0][r];
                float gf = acc[m][1][r];
                float gg = acc[m][2][r];
                float go = acc[m][3][r];
                float c  = c_r[m][r];
                c = fmaf(sigf(gf), c, sigf(gi) * tanhf_fast(gg));
                c_r[m][r] = c;
                float h = sigf(go) * tanhf_fast(c);
                unsigned short hh = f2bf_rne(h);
                float hres = h - bf2f(hh);
                int haddr = (m * 8 + kc_w) * 512
                          + ((4 * l4 + r) + 16 * kwhi) * 8 + elemw;
                hhi[p ^ 1][haddr] = hh;
                hlo[p ^ 1][haddr] = f2bf_rne(hres);
                ps[m][r] = h * wfc;
            }
        }

        // reduce d partials over the 16-lane j-group
        #pragma unroll
        for (int m = 0; m < 2; ++m)
            #pragma unroll
            for (int r = 0; r < 4; ++r) {
                float s = ps[m][r];
                s += __shfl_xor(s, 1);
                s += __shfl_xor(s, 2);
                s += __shfl_xor(s, 4);
                s += __shfl_xor(s, 8);
                if (l15 == 0) dpart[wave][16 * m + 4 * l4 + r] = s;
            }
        __syncthreads();   // B_A: h(alt buf) + dpart visible

        // ---- final d = sum over 16 waves + b_fc ; feedback ----
        if (tid < BB) {
            float s = bfc;
            #pragma unroll
            for (int w = 0; w < 16; ++w) s += dpart[w][tid];
            inp_s[tid] = s;
            out[(size_t)(bbase + tid) * TLEN + t] = s;
        }
        __syncthreads();   // B_B: inp_s ready; weight/h reads of next step may begin
    }
}

extern "C" void kernel_launch(void* const* d_in, const int* in_sizes, int n_in,
                              void* d_out, int out_size, void* d_ws, size_t ws_size,
                              hipStream_t stream) {
    const float* x    = (const float*)d_in[0];
    const float* W_ih = (const float*)d_in[1];
    const float* W_hh = (const float*)d_in[2];
    const float* b_ih = (const float*)d_in[3];
    const float* b_hh = (const float*)d_in[4];
    const float* W_fc = (const float*)d_in[5];
    const float* b_fc = (const float*)d_in[6];
    float* out = (float*)d_out;

    const int BATCH   = in_sizes[0];        // 8192
    const int nblocks = BATCH / BB;         // 256 -> 1 block/CU

    // replicate weight image: one copy per XCD if workspace allows (pow2 copies)
    int ncopies = 1;
    while (ncopies < 8 && (size_t)(ncopies * 2) * WP_BYTES <= ws_size) ncopies *= 2;
    const int copy_mask = ncopies - 1;

    dim3 pgrid(128, ncopies);
    pack_whh<<<pgrid, 256, 0, stream>>>(W_hh, (unsigned short*)d_ws);
    lstm_mfma4<<<nblocks, NTHR, 0, stream>>>(
        x, W_ih, b_ih, b_hh, W_fc, b_fc, (const short8*)d_ws, copy_mask, out);
}